// Round 1
// baseline (120.282 us; speedup 1.0000x reference)
//
#include <hip/hip_runtime.h>
#include <stdint.h>

#define CIN 256
#define COUT 128
#define BATCH 8
#define HH 64
#define WW 64
#define XROW 66

// xb2: padded bf16 input, [B][66 rows][66 cols][4 cb][8 slot][8 ch], slot pre-swizzled by (col&7)
#define XB2_BYTES ((size_t)BATCH * XROW * XROW * CIN * 2)
// gw2: fused weights, [9 taps][4 pm][4 cb][128 co][8 slot][8 ch], slot pre-swizzled by (co&7)
#define GW2_BYTES ((size_t)9 * 4 * 4 * 128 * 64 * 2)

typedef __bf16 bf16x8 __attribute__((ext_vector_type(8)));
typedef float f32x4 __attribute__((ext_vector_type(4)));

__device__ __forceinline__ unsigned short f2bf(float f) {
  unsigned int u = __float_as_uint(f);
  u += 0x7fffu + ((u >> 16) & 1u);
  return (unsigned short)(u >> 16);
}

__device__ __forceinline__ void gload_lds16(const void* g, void* l) {
  __builtin_amdgcn_global_load_lds(
      (__attribute__((address_space(1))) void*)(uintptr_t)g,
      (__attribute__((address_space(3))) void*)l, 16, 0, 0);
}

// ---------------- prep: x -> padded channel-last swizzled bf16 ----------------
__global__ __launch_bounds__(256) void prep_x(const float* __restrict__ x,
                                              unsigned short* __restrict__ xb2) {
  int b = blockIdx.x >> 6, iy = blockIdx.x & 63;
  __shared__ __align__(16) unsigned short lds[64][264];  // [ix][c], 528B rows (16B-divisible)
  int t = threadIdx.x;
  int cq = t >> 6, ix = t & 63;
  for (int ci = 0; ci < 64; ++ci) {
    int c = ci * 4 + cq;
    float v = x[(((size_t)b * CIN + c) * HH + iy) * WW + ix];
    lds[ix][c] = f2bf(v);
  }
  __syncthreads();
  for (int it = 0; it < 8; ++it) {
    int u = it * 256 + t;         // 2048 units of 16B: 64 ix * 32 (cb,slot)
    int ixo = u >> 5;
    int q = u & 31, cb = q >> 3, slot = q & 7;
    int col = ixo + 1;            // padded col
    int c0 = cb * 64 + 8 * (slot ^ (col & 7));
    uint4 val = *reinterpret_cast<const uint4*>(&lds[ixo][c0]);
    size_t o = ((((size_t)(b * XROW + (iy + 1)) * XROW + col) * 4 + cb) * 8 + slot) * 8;
    *reinterpret_cast<uint4*>(&xb2[o]) = val;
  }
}

// ---------------- prep: fuse He-scale * conv3x3 (x) FIR into per-parity 3x3 taps ----------------
__global__ __launch_bounds__(256) void prep_w(const float* __restrict__ w,
                                              const float* __restrict__ f,
                                              unsigned short* __restrict__ gw2) {
  __shared__ float fs[16];
  int co = blockIdx.x;
  int c = threadIdx.x;
  if (c < 16) fs[c] = f[c];
  __syncthreads();
  float wl[3][3];
  const float he = 1.0f / 48.0f;  // 1/sqrt(256*9)
#pragma unroll
  for (int dy = 0; dy < 3; ++dy)
#pragma unroll
    for (int dx = 0; dx < 3; ++dx)
      wl[dy][dx] = w[((size_t)(co * CIN + c) * 3 + dy) * 3 + dx] * he;
  int cb = c >> 6, cl = c & 63;
  int slot = (cl >> 3) ^ (co & 7);
  int ce = cl & 7;
  for (int d = 0; d < 3; ++d)
    for (int e = 0; e < 3; ++e)
      for (int py = 0; py < 2; ++py)
        for (int px = 0; px < 2; ++px) {
          int ty = 2 * d + 1 - py, tx = 2 * e + 1 - px;  // taps of 6x6 composite g
          float acc = 0.f;
          for (int dy = 0; dy < 3; ++dy) {
            int a = ty - dy;
            if (a < 0 || a > 3) continue;
            for (int dx = 0; dx < 3; ++dx) {
              int bb = tx - dx;
              if (bb < 0 || bb > 3) continue;
              acc += wl[dy][dx] * fs[a * 4 + bb];
            }
          }
          int pm = py * 2 + px;
          size_t o = ((((size_t)((d * 3 + e) * 4 + pm) * 4 + cb) * 128 + co) * 8 + slot) * 8 + ce;
          gw2[o] = f2bf(acc);
        }
}

// ---------------- main: implicit-GEMM polyphase conv, 128x128 tile, 4 waves ----------------
__global__ __launch_bounds__(256, 3) void conv_main(
    const unsigned short* __restrict__ xb2,
    const unsigned short* __restrict__ gw2,
    const float* __restrict__ bias,
    float* __restrict__ out) {
  __shared__ __align__(16) unsigned char smem[16384 + 33792];
  unsigned short* atile = (unsigned short*)smem;             // [128 co][8 slot][8 ch]
  unsigned short* xtile = (unsigned short*)(smem + 16384);   // [4 row][66 col][8 slot][8 ch]

  const int bid = blockIdx.x;
  const int pm = bid >> 8;   // parity 0..3
  const int nb = bid & 255;  // spatial block
  const int b = nb >> 5;
  const int m0 = (nb & 31) * 2;  // 2 output sub-rows per block
  const int py = pm >> 1, px = pm & 1;

  const int t = threadIdx.x;
  const int lane = t & 63;
  const int wave = t >> 6;
  const int wm = wave >> 1, wn = wave & 1;
  const int l15 = lane & 15, l4 = lane >> 4;

  f32x4 acc[4][4] = {};

  const char* xbase = (const char*)xb2 + (size_t)((b * XROW + m0) * (XROW * 32)) * 16;
  const char* gbase = (const char*)gw2;

  for (int cb = 0; cb < 4; ++cb) {
    for (int de = 0; de < 9; ++de) {
      {  // stage A tile (16 KB, linear, pre-swizzled in global)
        const char* g = gbase + (((size_t)(de * 4 + pm) * 4 + cb) << 14);
        int off = t * 16;
        gload_lds16(g + off, (char*)atile + off);
        gload_lds16(g + off + 4096, (char*)atile + off + 4096);
        gload_lds16(g + off + 8192, (char*)atile + off + 8192);
        gload_lds16(g + off + 12288, (char*)atile + off + 12288);
      }
      if (de == 0) {  // stage x halo tile for this channel block (33 KB), reused by 9 taps
        for (int it = 0; it < 9; ++it) {
          int u = it * 256 + t;  // 2112 units of 16B (wave-granular: 33 full waves)
          if (u < 2112) {
            int r = u / 528;
            int rem = u - r * 528;
            int col = rem >> 3, slot = rem & 7;
            int go = (r * XROW + col) * 32 + cb * 8 + slot;
            gload_lds16(xbase + (size_t)go * 16, (char*)xtile + (size_t)u * 16);
          }
        }
      }
      __syncthreads();
      const int d = de / 3, e = de - d * 3;
#pragma unroll
      for (int k8 = 0; k8 < 2; ++k8) {
        bf16x8 af[4], bfr[4];
#pragma unroll
        for (int i = 0; i < 4; ++i) {
          int row = wm * 64 + i * 16 + l15;
          int slot = (k8 * 4 + l4) ^ (row & 7);
          af[i] = *(const bf16x8*)(atile + ((size_t)row * 8 + slot) * 8);
        }
#pragma unroll
        for (int j = 0; j < 4; ++j) {
          int s = wn * 64 + j * 16 + l15;
          int mm = s >> 6, n = s & 63;
          int col = n + e;
          int slot = (k8 * 4 + l4) ^ (col & 7);
          bfr[j] = *(const bf16x8*)(xtile + (((size_t)(mm + d) * XROW + col) * 8 + slot) * 8);
        }
#pragma unroll
        for (int i = 0; i < 4; ++i)
#pragma unroll
          for (int j = 0; j < 4; ++j)
            acc[i][j] = __builtin_amdgcn_mfma_f32_16x16x32_bf16(af[i], bfr[j], acc[i][j], 0, 0, 0);
      }
      __syncthreads();
    }
  }

  const float kSqrt2 = 1.41421356237309515f;
#pragma unroll
  for (int i = 0; i < 4; ++i) {
    const int co0 = wm * 64 + i * 16 + l4 * 4;
#pragma unroll
    for (int j = 0; j < 4; ++j) {
      const int s = wn * 64 + j * 16 + l15;
      const int mm = s >> 6, n = s & 63;
      const int oh = 2 * (m0 + mm) + py;
      const int ow = 2 * n + px;
#pragma unroll
      for (int r = 0; r < 4; ++r) {
        const int co = co0 + r;
        float v = acc[i][j][r] + bias[co];
        v = (v < 0.f ? 0.01f * v : v) * kSqrt2;
        v = fminf(fmaxf(v, -256.f), 265.f);
        out[(((size_t)b * COUT + co) * 128 + oh) * 128 + ow] = v;
      }
    }
  }
}

extern "C" void kernel_launch(void* const* d_in, const int* in_sizes, int n_in,
                              void* d_out, int out_size, void* d_ws, size_t ws_size,
                              hipStream_t stream) {
  const float* x = (const float*)d_in[0];
  const float* w = (const float*)d_in[1];
  const float* bias = (const float*)d_in[2];
  const float* f = (const float*)d_in[3];
  float* out = (float*)d_out;

  unsigned short* xb2 = (unsigned short*)d_ws;
  unsigned short* gw2 = (unsigned short*)((char*)d_ws + XB2_BYTES);

  hipMemsetAsync(d_ws, 0, XB2_BYTES, stream);  // zero border of xb2
  hipLaunchKernelGGL(prep_x, dim3(BATCH * HH), dim3(256), 0, stream, x, xb2);
  hipLaunchKernelGGL(prep_w, dim3(128), dim3(256), 0, stream, w, f, gw2);
  hipLaunchKernelGGL(conv_main, dim3(1024), dim3(256), 0, stream, xb2, gw2, bias, out);
}

// Round 2
// 105.303 us; speedup vs baseline: 1.1423x; 1.1423x over previous
//
#include <hip/hip_runtime.h>
#include <stdint.h>

#define CIN 256
#define COUT 128
#define BATCH 8
#define HH 64
#define WW 64
#define XROW 66

// xb2: padded bf16 input, [B][66 rows][66 cols][4 cb][8 slot][8 ch], slot pre-swizzled by (col&7)
#define XB2_BYTES ((size_t)BATCH * XROW * XROW * CIN * 2)
// gw3: fused weights, [9 taps][2 py][4 cb][256 row=co*2+px][8 slot][8 ch], slot pre-swizzled by (row&7)
#define GW3_BYTES ((size_t)9 * 2 * 4 * 256 * 64 * 2)

typedef __bf16 bf16x8 __attribute__((ext_vector_type(8)));
typedef float f32x4 __attribute__((ext_vector_type(4)));

__device__ __forceinline__ unsigned short f2bf(float f) {
  unsigned int u = __float_as_uint(f);
  u += 0x7fffu + ((u >> 16) & 1u);
  return (unsigned short)(u >> 16);
}

__device__ __forceinline__ void gload_lds16(const void* g, void* l) {
  __builtin_amdgcn_global_load_lds(
      (__attribute__((address_space(1))) void*)(uintptr_t)g,
      (__attribute__((address_space(3))) void*)l, 16, 0, 0);
}

// ---------------- prep: x -> padded channel-last swizzled bf16 ----------------
__global__ __launch_bounds__(256) void prep_x(const float* __restrict__ x,
                                              unsigned short* __restrict__ xb2) {
  int b = blockIdx.x >> 6, iy = blockIdx.x & 63;
  __shared__ __align__(16) unsigned short lds[64][264];  // [ix][c]
  int t = threadIdx.x;
  int cq = t >> 6, ix = t & 63;
  for (int ci = 0; ci < 64; ++ci) {
    int c = ci * 4 + cq;
    float v = x[(((size_t)b * CIN + c) * HH + iy) * WW + ix];
    lds[ix][c] = f2bf(v);
  }
  __syncthreads();
  for (int it = 0; it < 8; ++it) {
    int u = it * 256 + t;  // 2048 units of 16B: 64 ix * 32 (cb,slot)
    int ixo = u >> 5;
    int q = u & 31, cb = q >> 3, slot = q & 7;
    int col = ixo + 1;  // padded col
    int c0 = cb * 64 + 8 * (slot ^ (col & 7));
    uint4 val = *reinterpret_cast<const uint4*>(&lds[ixo][c0]);
    size_t o = ((((size_t)(b * XROW + (iy + 1)) * XROW + col) * 4 + cb) * 8 + slot) * 8;
    *reinterpret_cast<uint4*>(&xb2[o]) = val;
  }
}

// ---------------- prep: fuse He-scale * conv3x3 (x) FIR into per-parity 3x3 taps ----------------
__global__ __launch_bounds__(256) void prep_w(const float* __restrict__ w,
                                              const float* __restrict__ f,
                                              unsigned short* __restrict__ gw3) {
  __shared__ float fs[16];
  int co = blockIdx.x;
  int c = threadIdx.x;
  if (c < 16) fs[c] = f[c];
  __syncthreads();
  float wl[3][3];
  const float he = 1.0f / 48.0f;  // 1/sqrt(256*9)
#pragma unroll
  for (int dy = 0; dy < 3; ++dy)
#pragma unroll
    for (int dx = 0; dx < 3; ++dx)
      wl[dy][dx] = w[((size_t)(co * CIN + c) * 3 + dy) * 3 + dx] * he;
  int cb = c >> 6, cl = c & 63;
  int ce = cl & 7;
  for (int d = 0; d < 3; ++d)
    for (int e = 0; e < 3; ++e)
      for (int py = 0; py < 2; ++py)
        for (int px = 0; px < 2; ++px) {
          int ty = 2 * d + 1 - py, tx = 2 * e + 1 - px;  // taps of 6x6 composite g
          float acc = 0.f;
          for (int dy = 0; dy < 3; ++dy) {
            int a = ty - dy;
            if (a < 0 || a > 3) continue;
            for (int dx = 0; dx < 3; ++dx) {
              int bb = tx - dx;
              if (bb < 0 || bb > 3) continue;
              acc += wl[dy][dx] * fs[a * 4 + bb];
            }
          }
          int row = co * 2 + px;
          int slot = (cl >> 3) ^ (row & 7);
          size_t o = ((((size_t)(d * 3 + e) * 2 + py) * 4 + cb) * 256 + row) * 64 + slot * 8 + ce;
          gw3[o] = f2bf(acc);
        }
}

// ---------------- main: implicit-GEMM polyphase conv, 256x128 tile, 8 waves ----------------
// M=256 (row = co*2+px), N=128 spatial (2 out sub-rows x 64 cols), K=2304 in 36 steps of 64.
// Counted-vmcnt double-buffered A staging; X halo staged once per cb (reused by 9 taps).
__global__ __launch_bounds__(512, 2) void conv_main(
    const unsigned short* __restrict__ xb2,
    const unsigned short* __restrict__ gw3,
    const float* __restrict__ bias,
    float* __restrict__ out) {
  __shared__ __align__(16) unsigned char smem[65536 + 33792];
  unsigned short* at0 = (unsigned short*)smem;              // A buf 0: [256 row][8 slot][8 ch]
  unsigned short* at1 = (unsigned short*)(smem + 32768);    // A buf 1
  unsigned short* xt = (unsigned short*)(smem + 65536);     // X: [4 row][66 col][8 slot][8 ch]

  const int bid = blockIdx.x;
  const int py = bid >> 8;   // 0..1
  const int nb = bid & 255;
  const int b = nb >> 5;
  const int m0 = (nb & 31) * 2;  // 2 output sub-rows per block

  const int t = threadIdx.x;
  const int lane = t & 63;
  const int wave = t >> 6;
  const int wm = wave >> 1, wn = wave & 1;  // 4 x 2 wave grid
  const int l15 = lane & 15, l4 = lane >> 4;

  f32x4 acc[4][4] = {};

  const char* xbase = (const char*)xb2 + (size_t)((b * XROW + m0) * (XROW * 32)) * 16;

#define STAGE_A(buf, de, cbv)                                                   \
  do {                                                                          \
    const char* g = (const char*)gw3 + ((((size_t)(de)*2 + py) * 4 + (cbv)) << 15); \
    int off = t * 16;                                                           \
    gload_lds16(g + off, (char*)(buf) + off);                                   \
    gload_lds16(g + off + 8192, (char*)(buf) + off + 8192);                     \
    gload_lds16(g + off + 16384, (char*)(buf) + off + 16384);                   \
    gload_lds16(g + off + 24576, (char*)(buf) + off + 24576);                   \
  } while (0)

#define STAGE_X(cbv)                                                            \
  do {                                                                          \
    for (int it = 0; it < 5; ++it) {                                            \
      int u = it * 512 + t; /* 2112 units of 16B; it=4 is wave 0 only */        \
      if (u < 2112) {                                                           \
        int r = u / 528;                                                        \
        int rem = u - r * 528;                                                  \
        int col = rem >> 3, slot = rem & 7;                                     \
        size_t go = (size_t)(r * XROW + col) * 32 + (cbv) * 8 + slot;           \
        gload_lds16(xbase + go * 16, (char*)xt + (size_t)u * 16);               \
      }                                                                         \
    }                                                                           \
  } while (0)

  // prologue: first A tile + first X tile in flight
  STAGE_A(at0, 0, 0);
  STAGE_X(0);

  for (int s = 0; s < 36; ++s) {
    const int cb = s / 9, de = s - cb * 9;
    const unsigned short* A = (s & 1) ? at1 : at0;
    unsigned short* An = (s & 1) ? at0 : at1;
    if (s < 35) {
      const int sn = s + 1;
      const int cbn = sn / 9, den = sn - cbn * 9;
      STAGE_A(An, den, cbn);  // next A in flight across the barrier
      asm volatile("s_waitcnt vmcnt(4)" ::: "memory");  // cur A + X done; next A outstanding
    } else {
      asm volatile("s_waitcnt vmcnt(0)" ::: "memory");
    }
    __builtin_amdgcn_s_barrier();
    asm volatile("" ::: "memory");

    const int d = de / 3, e = de - d * 3;
#pragma unroll
    for (int k8 = 0; k8 < 2; ++k8) {
      bf16x8 af[4], bfr[4];
#pragma unroll
      for (int i = 0; i < 4; ++i) {
        int row = wm * 64 + i * 16 + l15;
        int slot = (k8 * 4 + l4) ^ (row & 7);
        af[i] = *(const bf16x8*)(A + (size_t)row * 64 + slot * 8);
      }
#pragma unroll
      for (int j = 0; j < 4; ++j) {
        int sN = wn * 64 + j * 16 + l15;
        int mm = sN >> 6, n = sN & 63;
        int col = n + e;
        int slot = (k8 * 4 + l4) ^ (col & 7);
        bfr[j] = *(const bf16x8*)(xt + ((size_t)(mm + d) * XROW + col) * 64 + slot * 8);
      }
#pragma unroll
      for (int i = 0; i < 4; ++i)
#pragma unroll
        for (int j = 0; j < 4; ++j)
          acc[i][j] = __builtin_amdgcn_mfma_f32_16x16x32_bf16(af[i], bfr[j], acc[i][j], 0, 0, 0);
    }

    asm volatile("" ::: "memory");
    __builtin_amdgcn_s_barrier();
    if (de == 8 && cb < 3) STAGE_X(cb + 1);  // X free now; covered by next step's vmcnt(4)
  }
#undef STAGE_A
#undef STAGE_X

  const float kSqrt2 = 1.41421356237309515f;
#pragma unroll
  for (int i = 0; i < 4; ++i) {
    const int row0 = wm * 64 + i * 16 + l4 * 4;  // even
    const int co0 = row0 >> 1;                   // r=0,1 -> co0 (px=0,1); r=2,3 -> co0+1
    const float bs0 = bias[co0], bs1 = bias[co0 + 1];
#pragma unroll
    for (int j = 0; j < 4; ++j) {
      const int sN = wn * 64 + j * 16 + l15;
      const int mm = sN >> 6, n = sN & 63;
      const int oh = 2 * (m0 + mm) + py;
      float v[4];
#pragma unroll
      for (int r = 0; r < 4; ++r) {
        float vv = acc[i][j][r] + ((r < 2) ? bs0 : bs1);
        vv = (vv < 0.f ? 0.01f * vv : vv) * kSqrt2;
        v[r] = fminf(fmaxf(vv, -256.f), 265.f);
      }
      float2* p0 = (float2*)&out[(((size_t)b * COUT + co0) * 128 + oh) * 128 + 2 * n];
      float2* p1 = (float2*)&out[(((size_t)b * COUT + co0 + 1) * 128 + oh) * 128 + 2 * n];
      *p0 = make_float2(v[0], v[1]);
      *p1 = make_float2(v[2], v[3]);
    }
  }
}

extern "C" void kernel_launch(void* const* d_in, const int* in_sizes, int n_in,
                              void* d_out, int out_size, void* d_ws, size_t ws_size,
                              hipStream_t stream) {
  const float* x = (const float*)d_in[0];
  const float* w = (const float*)d_in[1];
  const float* bias = (const float*)d_in[2];
  const float* f = (const float*)d_in[3];
  float* out = (float*)d_out;

  unsigned short* xb2 = (unsigned short*)d_ws;
  unsigned short* gw3 = (unsigned short*)((char*)d_ws + XB2_BYTES);

  hipMemsetAsync(d_ws, 0, XB2_BYTES, stream);  // zero border of xb2
  hipLaunchKernelGGL(prep_x, dim3(BATCH * HH), dim3(256), 0, stream, x, xb2);
  hipLaunchKernelGGL(prep_w, dim3(128), dim3(256), 0, stream, w, f, gw3);
  hipLaunchKernelGGL(conv_main, dim3(512), dim3(512), 0, stream, xb2, gw3, bias, out);
}

// Round 3
// 92.917 us; speedup vs baseline: 1.2945x; 1.1333x over previous
//
#include <hip/hip_runtime.h>
#include <stdint.h>

#define CIN 256
#define COUT 128
#define BATCH 8
#define HH 64
#define WW 64
#define XROW 66

// xb2: padded bf16 input, [B][66 rows][66 cols][4 cb][8 slot][8 ch], slot pre-swizzled by (col&7)
#define XB2_BYTES ((size_t)BATCH * XROW * XROW * CIN * 2)
// gw3: fused weights, [9 taps][2 py][4 cb][256 row=co*2+px][8 slot][8 ch], slot pre-swizzled by (row&7)
#define GW3_BYTES ((size_t)9 * 2 * 4 * 256 * 64 * 2)

typedef __bf16 bf16x8 __attribute__((ext_vector_type(8)));
typedef float f32x4 __attribute__((ext_vector_type(4)));

__device__ __forceinline__ unsigned short f2bf(float f) {
  unsigned int u = __float_as_uint(f);
  u += 0x7fffu + ((u >> 16) & 1u);
  return (unsigned short)(u >> 16);
}

__device__ __forceinline__ void gload_lds16(const void* g, void* l) {
  __builtin_amdgcn_global_load_lds(
      (__attribute__((address_space(1))) void*)(uintptr_t)g,
      (__attribute__((address_space(3))) void*)l, 16, 0, 0);
}

// ---------------- prep: x -> padded channel-last swizzled bf16 ----------------
__global__ __launch_bounds__(256) void prep_x(const float* __restrict__ x,
                                              unsigned short* __restrict__ xb2) {
  int b = blockIdx.x >> 6, iy = blockIdx.x & 63;
  __shared__ __align__(16) unsigned short lds[64][264];  // [ix][c]
  int t = threadIdx.x;
  int cq = t >> 6, ix = t & 63;
  for (int ci = 0; ci < 64; ++ci) {
    int c = ci * 4 + cq;
    float v = x[(((size_t)b * CIN + c) * HH + iy) * WW + ix];
    lds[ix][c] = f2bf(v);
  }
  __syncthreads();
  for (int it = 0; it < 8; ++it) {
    int u = it * 256 + t;  // 2048 units of 16B: 64 ix * 32 (cb,slot)
    int ixo = u >> 5;
    int q = u & 31, cb = q >> 3, slot = q & 7;
    int col = ixo + 1;  // padded col
    int c0 = cb * 64 + 8 * (slot ^ (col & 7));
    uint4 val = *reinterpret_cast<const uint4*>(&lds[ixo][c0]);
    size_t o = ((((size_t)(b * XROW + (iy + 1)) * XROW + col) * 4 + cb) * 8 + slot) * 8;
    *reinterpret_cast<uint4*>(&xb2[o]) = val;
  }
}

// ---------------- prep: fuse He-scale * conv3x3 (x) FIR into per-parity 3x3 taps ----------------
__global__ __launch_bounds__(256) void prep_w(const float* __restrict__ w,
                                              const float* __restrict__ f,
                                              unsigned short* __restrict__ gw3) {
  __shared__ float fs[16];
  int co = blockIdx.x;
  int c = threadIdx.x;
  if (c < 16) fs[c] = f[c];
  __syncthreads();
  float wl[3][3];
  const float he = 1.0f / 48.0f;  // 1/sqrt(256*9)
#pragma unroll
  for (int dy = 0; dy < 3; ++dy)
#pragma unroll
    for (int dx = 0; dx < 3; ++dx)
      wl[dy][dx] = w[((size_t)(co * CIN + c) * 3 + dy) * 3 + dx] * he;
  int cb = c >> 6, cl = c & 63;
  int ce = cl & 7;
  for (int d = 0; d < 3; ++d)
    for (int e = 0; e < 3; ++e)
      for (int py = 0; py < 2; ++py)
        for (int px = 0; px < 2; ++px) {
          int ty = 2 * d + 1 - py, tx = 2 * e + 1 - px;  // taps of 6x6 composite g
          float acc = 0.f;
          for (int dy = 0; dy < 3; ++dy) {
            int a = ty - dy;
            if (a < 0 || a > 3) continue;
            for (int dx = 0; dx < 3; ++dx) {
              int bb = tx - dx;
              if (bb < 0 || bb > 3) continue;
              acc += wl[dy][dx] * fs[a * 4 + bb];
            }
          }
          int row = co * 2 + px;
          int slot = (cl >> 3) ^ (row & 7);
          size_t o = ((((size_t)(d * 3 + e) * 2 + py) * 4 + cb) * 256 + row) * 64 + slot * 8 + ce;
          gw3[o] = f2bf(acc);
        }
}

// ---------------- main: implicit-GEMM polyphase conv, 256x256 tile, 8 waves ----------------
// M=256 (row = co*2+px), N=256 spatial (4 out sub-rows x 64 cols; wave wn owns sub-row wn),
// K=2304 in 36 steps of 64. 4-phase-per-step schedule (m201-style): per phase
// {ds_read A-quadrant (+B & A-prefetch at p0) -> bar -> lgkm(0) -> setprio(1) -> 16 MFMA
//  -> setprio(0) -> bar}; A prefetched 1 step ahead, drained by vmcnt(0) at phase 3 end.
__global__ __launch_bounds__(512, 2) void conv_main(
    const unsigned short* __restrict__ xb2,
    const unsigned short* __restrict__ gw3,
    const float* __restrict__ bias,
    float* __restrict__ out) {
  __shared__ __align__(16) unsigned char smem[65536 + 51200];
  unsigned short* at0 = (unsigned short*)smem;            // A buf 0: [256 row][8 slot][8 ch]
  unsigned short* at1 = (unsigned short*)(smem + 32768);  // A buf 1
  unsigned short* xt = (unsigned short*)(smem + 65536);   // X: [6 xrow][66 col][8 slot][8 ch]

  const int bid = blockIdx.x;
  const int py = bid >> 7;       // 0..1
  const int r0 = bid & 127;
  const int b = r0 >> 4;
  const int m0 = (r0 & 15) * 4;  // 4 output sub-rows per block

  const int t = threadIdx.x;
  const int lane = t & 63;
  const int wave = t >> 6;
  const int wm = wave >> 2;  // 0..1: M half
  const int wn = wave & 3;   // 0..3: output sub-row mm
  const int l15 = lane & 15, l4 = lane >> 4;

  f32x4 acc[8][4] = {};

  const char* xbase = (const char*)xb2 + (size_t)((b * XROW + m0) * (XROW * 32)) * 16;

#define STAGE_A(buf, de_, cb_)                                                        \
  do {                                                                                \
    const char* g = (const char*)gw3 + ((((size_t)(de_)*2 + py) * 4 + (cb_)) << 15);  \
    int off = t * 16;                                                                 \
    gload_lds16(g + off, (char*)(buf) + off);                                         \
    gload_lds16(g + off + 8192, (char*)(buf) + off + 8192);                           \
    gload_lds16(g + off + 16384, (char*)(buf) + off + 16384);                         \
    gload_lds16(g + off + 24576, (char*)(buf) + off + 24576);                         \
  } while (0)

  // X tile per cb: 6 rows x 66 cols x 8 slots = 3168 16B units, padded to 3200 (wave-granular tail)
#define STAGE_X(cb_)                                                          \
  do {                                                                        \
    for (int it = 0; it < 7; ++it) {                                          \
      int u = it * 512 + t;                                                   \
      if (u < 3200) {                                                         \
        int us = (u < 3168) ? u : (u - 64);                                   \
        int rr = us / 528;                                                    \
        int rem = us - rr * 528;                                              \
        int col = rem >> 3, slot = rem & 7;                                   \
        size_t go = (size_t)(rr * XROW + col) * 32 + (cb_) * 8 + slot;        \
        gload_lds16(xbase + go * 16, (char*)xt + (size_t)u * 16);             \
      }                                                                       \
    }                                                                         \
  } while (0)

#define BAR()                          \
  do {                                 \
    asm volatile("" ::: "memory");     \
    __builtin_amdgcn_s_barrier();      \
    asm volatile("" ::: "memory");     \
  } while (0)

  // phase P: read A-quadrant P, barrier, wait, 16 MFMA
#define PHASE_COMPUTE(P)                                                           \
  do {                                                                             \
    bf16x8 af[2][2];                                                               \
    _Pragma("unroll") for (int ii = 0; ii < 2; ++ii) {                             \
      int row = wm * 128 + (2 * (P) + ii) * 16 + l15;                              \
      _Pragma("unroll") for (int k8 = 0; k8 < 2; ++k8) {                           \
        int slot = (k8 * 4 + l4) ^ (row & 7);                                      \
        af[ii][k8] = *(const bf16x8*)(A + (size_t)row * 64 + slot * 8);            \
      }                                                                            \
    }                                                                              \
    BAR();                                                                         \
    asm volatile("s_waitcnt lgkmcnt(0)" ::: "memory");                             \
    __builtin_amdgcn_sched_barrier(0);                                             \
    __builtin_amdgcn_s_setprio(1);                                                 \
    _Pragma("unroll") for (int ii = 0; ii < 2; ++ii)                               \
      _Pragma("unroll") for (int j = 0; j < 4; ++j)                                \
        _Pragma("unroll") for (int k8 = 0; k8 < 2; ++k8)                           \
          acc[2 * (P) + ii][j] = __builtin_amdgcn_mfma_f32_16x16x32_bf16(          \
              af[ii][k8], bfr[j][k8], acc[2 * (P) + ii][j], 0, 0, 0);              \
    __builtin_amdgcn_s_setprio(0);                                                 \
    __builtin_amdgcn_sched_barrier(0);                                             \
  } while (0)

  // prologue
  STAGE_A(at0, 0, 0);
  STAGE_X(0);
  asm volatile("s_waitcnt vmcnt(0)" ::: "memory");
  BAR();

  for (int s = 0; s < 36; ++s) {
    const int cb = s / 9, de = s - cb * 9;
    const int d = de / 3, e = de - d * 3;
    const unsigned short* A = (s & 1) ? at1 : at0;
    unsigned short* An = (s & 1) ? at0 : at1;

    // ---- phase 0: A-prefetch issue + B-frag reads + quad 0 ----
    if (s < 35) {
      const int sn = s + 1;
      const int cbn = sn / 9, den = sn - cbn * 9;
      STAGE_A(An, den, cbn);
    }
    bf16x8 bfr[4][2];
    {
      const int xr = wn + d;
#pragma unroll
      for (int j = 0; j < 4; ++j) {
        const int col = j * 16 + l15 + e;
#pragma unroll
        for (int k8 = 0; k8 < 2; ++k8) {
          const int slot = (k8 * 4 + l4) ^ (col & 7);
          bfr[j][k8] = *(const bf16x8*)(xt + ((size_t)xr * 66 + col) * 64 + slot * 8);
        }
      }
    }
    PHASE_COMPUTE(0);
    BAR();
    // X buffer free for restage now (all waves consumed B-frags into regs)
    if (de == 8 && cb < 3) STAGE_X(cb + 1);
    PHASE_COMPUTE(1);
    BAR();
    PHASE_COMPUTE(2);
    BAR();
    PHASE_COMPUTE(3);
    asm volatile("s_waitcnt vmcnt(0)" ::: "memory");  // drain A[s+1] (+X at boundaries)
    BAR();
  }
#undef STAGE_A
#undef STAGE_X
#undef PHASE_COMPUTE

  const float kSqrt2 = 1.41421356237309515f;
  const int oh = 2 * (m0 + wn) + py;
#pragma unroll
  for (int i = 0; i < 8; ++i) {
    const int row0 = wm * 128 + i * 16 + l4 * 4;  // even
    const int co0 = row0 >> 1;                    // r=0,1 -> co0 (px=0,1); r=2,3 -> co0+1
    const float bs0 = bias[co0], bs1 = bias[co0 + 1];
#pragma unroll
    for (int j = 0; j < 4; ++j) {
      const int n = j * 16 + l15;
      float v[4];
#pragma unroll
      for (int r = 0; r < 4; ++r) {
        float vv = acc[i][j][r] + ((r < 2) ? bs0 : bs1);
        vv = (vv < 0.f ? 0.01f * vv : vv) * kSqrt2;
        v[r] = fminf(fmaxf(vv, -256.f), 265.f);
      }
      float2* p0 = (float2*)&out[(((size_t)b * COUT + co0) * 128 + oh) * 128 + 2 * n];
      float2* p1 = (float2*)&out[(((size_t)b * COUT + co0 + 1) * 128 + oh) * 128 + 2 * n];
      *p0 = make_float2(v[0], v[1]);
      *p1 = make_float2(v[2], v[3]);
    }
  }
}

extern "C" void kernel_launch(void* const* d_in, const int* in_sizes, int n_in,
                              void* d_out, int out_size, void* d_ws, size_t ws_size,
                              hipStream_t stream) {
  const float* x = (const float*)d_in[0];
  const float* w = (const float*)d_in[1];
  const float* bias = (const float*)d_in[2];
  const float* f = (const float*)d_in[3];
  float* out = (float*)d_out;

  unsigned short* xb2 = (unsigned short*)d_ws;
  unsigned short* gw3 = (unsigned short*)((char*)d_ws + XB2_BYTES);

  hipMemsetAsync(d_ws, 0, XB2_BYTES, stream);  // zero border of xb2
  hipLaunchKernelGGL(prep_x, dim3(BATCH * HH), dim3(256), 0, stream, x, xb2);
  hipLaunchKernelGGL(prep_w, dim3(128), dim3(256), 0, stream, w, f, gw3);
  hipLaunchKernelGGL(conv_main, dim3(256), dim3(512), 0, stream, xb2, gw3, bias, out);
}

// Round 4
// 92.916 us; speedup vs baseline: 1.2945x; 1.0000x over previous
//
#include <hip/hip_runtime.h>
#include <stdint.h>

#define CIN 256
#define COUT 128
#define BATCH 8
#define HH 64
#define WW 64
#define XROW 66

// xb2: padded bf16 input, [B][66 rows][66 cols][4 cb][8 slot][8 ch], slot pre-swizzled by (col&7)
#define XB2_BYTES ((size_t)BATCH * XROW * XROW * CIN * 2)
// gw3: fused weights, [9 taps][2 py][4 cb][256 row=co*2+px][8 slot][8 ch], slot pre-swizzled by (row&7)
#define GW3_BYTES ((size_t)9 * 2 * 4 * 256 * 64 * 2)

typedef __bf16 bf16x8 __attribute__((ext_vector_type(8)));
typedef float f32x4 __attribute__((ext_vector_type(4)));

__device__ __forceinline__ unsigned short f2bf(float f) {
  unsigned int u = __float_as_uint(f);
  u += 0x7fffu + ((u >> 16) & 1u);
  return (unsigned short)(u >> 16);
}

__device__ __forceinline__ void gload_lds16(const void* g, void* l) {
  __builtin_amdgcn_global_load_lds(
      (__attribute__((address_space(1))) void*)(uintptr_t)g,
      (__attribute__((address_space(3))) void*)l, 16, 0, 0);
}

// ---------------- prep: x -> padded channel-last swizzled bf16 ----------------
__global__ __launch_bounds__(256) void prep_x(const float* __restrict__ x,
                                              unsigned short* __restrict__ xb2) {
  int b = blockIdx.x >> 6, iy = blockIdx.x & 63;
  __shared__ __align__(16) unsigned short lds[64][264];  // [ix][c]
  int t = threadIdx.x;
  int cq = t >> 6, ix = t & 63;
  for (int ci = 0; ci < 64; ++ci) {
    int c = ci * 4 + cq;
    float v = x[(((size_t)b * CIN + c) * HH + iy) * WW + ix];
    lds[ix][c] = f2bf(v);
  }
  __syncthreads();
  for (int it = 0; it < 8; ++it) {
    int u = it * 256 + t;  // 2048 units of 16B: 64 ix * 32 (cb,slot)
    int ixo = u >> 5;
    int q = u & 31, cb = q >> 3, slot = q & 7;
    int col = ixo + 1;  // padded col
    int c0 = cb * 64 + 8 * (slot ^ (col & 7));
    uint4 val = *reinterpret_cast<const uint4*>(&lds[ixo][c0]);
    size_t o = ((((size_t)(b * XROW + (iy + 1)) * XROW + col) * 4 + cb) * 8 + slot) * 8;
    *reinterpret_cast<uint4*>(&xb2[o]) = val;
  }
}

// ---------------- prep: fuse He-scale * conv3x3 (x) FIR into per-parity 3x3 taps ----------------
__global__ __launch_bounds__(256) void prep_w(const float* __restrict__ w,
                                              const float* __restrict__ f,
                                              unsigned short* __restrict__ gw3) {
  __shared__ float fs[16];
  int co = blockIdx.x;
  int c = threadIdx.x;
  if (c < 16) fs[c] = f[c];
  __syncthreads();
  float wl[3][3];
  const float he = 1.0f / 48.0f;  // 1/sqrt(256*9)
#pragma unroll
  for (int dy = 0; dy < 3; ++dy)
#pragma unroll
    for (int dx = 0; dx < 3; ++dx)
      wl[dy][dx] = w[((size_t)(co * CIN + c) * 3 + dy) * 3 + dx] * he;
  int cb = c >> 6, cl = c & 63;
  int ce = cl & 7;
  for (int d = 0; d < 3; ++d)
    for (int e = 0; e < 3; ++e)
      for (int py = 0; py < 2; ++py)
        for (int px = 0; px < 2; ++px) {
          int ty = 2 * d + 1 - py, tx = 2 * e + 1 - px;  // taps of 6x6 composite g
          float acc = 0.f;
          for (int dy = 0; dy < 3; ++dy) {
            int a = ty - dy;
            if (a < 0 || a > 3) continue;
            for (int dx = 0; dx < 3; ++dx) {
              int bb = tx - dx;
              if (bb < 0 || bb > 3) continue;
              acc += wl[dy][dx] * fs[a * 4 + bb];
            }
          }
          int row = co * 2 + px;
          int slot = (cl >> 3) ^ (row & 7);
          size_t o = ((((size_t)(d * 3 + e) * 2 + py) * 4 + cb) * 256 + row) * 64 + slot * 8 + ce;
          gw3[o] = f2bf(acc);
        }
}

// ---------------- main: implicit-GEMM polyphase conv, 256x256 tile, 8 waves ----------------
// M=256 (row = co*2+px), N=256 spatial (4 out sub-rows x 64 cols; wave wn owns sub-row wn),
// K=2304 in 36 steps of 64. K-major 2-phase schedule: per phase
// {2x global_load_lds (A half, next step) | 12 ds_read_b128 (af[8]+bfr[4], one k8-half)
//  -> bar -> lgkm(0) -> setprio(1) -> 32 MFMA -> setprio(0)}; 4 barriers/step;
// A prefetched 1 step ahead, drained by vmcnt(0) at step end (issue->drain ~1 step >> L2 lat).
__global__ __launch_bounds__(512, 2) void conv_main(
    const unsigned short* __restrict__ xb2,
    const unsigned short* __restrict__ gw3,
    const float* __restrict__ bias,
    float* __restrict__ out) {
  __shared__ __align__(16) unsigned char smem[65536 + 51200];
  unsigned short* at0 = (unsigned short*)smem;            // A buf 0: [256 row][8 slot][8 ch]
  unsigned short* at1 = (unsigned short*)(smem + 32768);  // A buf 1
  unsigned short* xt = (unsigned short*)(smem + 65536);   // X: [6 xrow][66 col][8 slot][8 ch]

  const int bid = blockIdx.x;
  const int py = bid >> 7;       // 0..1
  const int r0 = bid & 127;
  const int b = r0 >> 4;
  const int m0 = (r0 & 15) * 4;  // 4 output sub-rows per block

  const int t = threadIdx.x;
  const int lane = t & 63;
  const int wave = t >> 6;
  const int wm = wave >> 2;  // 0..1: M half
  const int wn = wave & 3;   // 0..3: output sub-row mm
  const int l15 = lane & 15, l4 = lane >> 4;

  f32x4 acc[8][4] = {};

  const char* xbase = (const char*)xb2 + (size_t)((b * XROW + m0) * (XROW * 32)) * 16;

  // stage one 16KB half of the next A tile (2 gloads/thread)
#define STAGE_A_HALF(buf, de_, cb_, H)                                                    \
  do {                                                                                    \
    const char* g = (const char*)gw3 + ((((size_t)(de_)*2 + py) * 4 + (cb_)) << 15) +     \
                    (H)*16384;                                                            \
    int off = (H)*16384 + t * 16;                                                         \
    gload_lds16(g + t * 16, (char*)(buf) + off);                                          \
    gload_lds16(g + t * 16 + 8192, (char*)(buf) + off + 8192);                            \
  } while (0)

  // X tile per cb: 6 rows x 66 cols x 8 slots = 3168 16B units, padded to 3200 (wave-granular tail)
#define STAGE_X(cb_)                                                          \
  do {                                                                        \
    for (int it = 0; it < 7; ++it) {                                          \
      int u = it * 512 + t;                                                   \
      if (u < 3200) {                                                         \
        int us = (u < 3168) ? u : (u - 64);                                   \
        int rr = us / 528;                                                    \
        int rem = us - rr * 528;                                              \
        int col = rem >> 3, slot = rem & 7;                                   \
        size_t go = (size_t)(rr * XROW + col) * 32 + (cb_) * 8 + slot;        \
        gload_lds16(xbase + go * 16, (char*)xt + (size_t)u * 16);             \
      }                                                                       \
    }                                                                         \
  } while (0)

#define BAR()                        \
  do {                               \
    asm volatile("" ::: "memory");   \
    __builtin_amdgcn_s_barrier();    \
    asm volatile("" ::: "memory");   \
  } while (0)

  // one K-half phase: 12 ds_reads -> bar -> (opt X stage) -> lgkm(0) -> 32 MFMA
#define KPHASE(K8, XSTMT)                                                                 \
  do {                                                                                    \
    bf16x8 af[8], bfv[4];                                                                 \
    _Pragma("unroll") for (int i = 0; i < 8; ++i) {                                       \
      int row = wm * 128 + i * 16 + l15;                                                  \
      int slot = ((K8)*4 + l4) ^ (row & 7);                                               \
      af[i] = *(const bf16x8*)(A + (size_t)row * 64 + slot * 8);                          \
    }                                                                                     \
    _Pragma("unroll") for (int j = 0; j < 4; ++j) {                                       \
      int col = j * 16 + l15 + e;                                                         \
      int slot = ((K8)*4 + l4) ^ (col & 7);                                               \
      bfv[j] = *(const bf16x8*)(xt + ((size_t)xr * 66 + col) * 64 + slot * 8);            \
    }                                                                                     \
    BAR();                                                                                \
    XSTMT;                                                                                \
    asm volatile("s_waitcnt lgkmcnt(0)" ::: "memory");                                    \
    __builtin_amdgcn_sched_barrier(0);                                                    \
    __builtin_amdgcn_s_setprio(1);                                                        \
    _Pragma("unroll") for (int i = 0; i < 8; ++i)                                         \
      _Pragma("unroll") for (int j = 0; j < 4; ++j)                                       \
        acc[i][j] =                                                                       \
            __builtin_amdgcn_mfma_f32_16x16x32_bf16(af[i], bfv[j], acc[i][j], 0, 0, 0);   \
    __builtin_amdgcn_s_setprio(0);                                                        \
    __builtin_amdgcn_sched_barrier(0);                                                    \
  } while (0)

  // prologue: first A tile + first X tile
  STAGE_A_HALF(at0, 0, 0, 0);
  STAGE_A_HALF(at0, 0, 0, 1);
  STAGE_X(0);
  asm volatile("s_waitcnt vmcnt(0)" ::: "memory");
  BAR();

  unsigned short* A = at0;
  unsigned short* An = at1;
  int cb = 0, de = 0, d = 0, e = 0;
  for (int s = 0; s < 36; ++s) {
    const int xr = wn + d;
    const int notlast = (s < 35);
    const int nde = (de == 8) ? 0 : de + 1;
    const int ncb = (de == 8) ? cb + 1 : cb;

    if (notlast) STAGE_A_HALF(An, nde, ncb, 0);
    KPHASE(0, {});
    BAR();
    if (notlast) STAGE_A_HALF(An, nde, ncb, 1);
    KPHASE(1, {
      if (de == 8 && cb < 3) STAGE_X(cb + 1);  // xt reads done at this phase's barrier
    });
    asm volatile("s_waitcnt vmcnt(0)" ::: "memory");  // next A (+X at boundary) complete
    BAR();

    { unsigned short* tmp = A; A = An; An = tmp; }
    ++e;
    if (e == 3) { e = 0; ++d; }
    ++de;
    if (de == 9) { de = 0; d = 0; e = 0; ++cb; }
  }
#undef STAGE_A_HALF
#undef STAGE_X
#undef KPHASE

  const float kSqrt2 = 1.41421356237309515f;
  const int oh = 2 * (m0 + wn) + py;
#pragma unroll
  for (int i = 0; i < 8; ++i) {
    const int row0 = wm * 128 + i * 16 + l4 * 4;  // even
    const int co0 = row0 >> 1;                    // r=0,1 -> co0 (px=0,1); r=2,3 -> co0+1
    const float bs0 = bias[co0], bs1 = bias[co0 + 1];
#pragma unroll
    for (int j = 0; j < 4; ++j) {
      const int n = j * 16 + l15;
      float v[4];
#pragma unroll
      for (int r = 0; r < 4; ++r) {
        float vv = acc[i][j][r] + ((r < 2) ? bs0 : bs1);
        vv = (vv < 0.f ? 0.01f * vv : vv) * kSqrt2;
        v[r] = fminf(fmaxf(vv, -256.f), 265.f);
      }
      float2* p0 = (float2*)&out[(((size_t)b * COUT + co0) * 128 + oh) * 128 + 2 * n];
      float2* p1 = (float2*)&out[(((size_t)b * COUT + co0 + 1) * 128 + oh) * 128 + 2 * n];
      *p0 = make_float2(v[0], v[1]);
      *p1 = make_float2(v[2], v[3]);
    }
  }
}

extern "C" void kernel_launch(void* const* d_in, const int* in_sizes, int n_in,
                              void* d_out, int out_size, void* d_ws, size_t ws_size,
                              hipStream_t stream) {
  const float* x = (const float*)d_in[0];
  const float* w = (const float*)d_in[1];
  const float* bias = (const float*)d_in[2];
  const float* f = (const float*)d_in[3];
  float* out = (float*)d_out;

  unsigned short* xb2 = (unsigned short*)d_ws;
  unsigned short* gw3 = (unsigned short*)((char*)d_ws + XB2_BYTES);

  hipMemsetAsync(d_ws, 0, XB2_BYTES, stream);  // zero border of xb2
  hipLaunchKernelGGL(prep_x, dim3(BATCH * HH), dim3(256), 0, stream, x, xb2);
  hipLaunchKernelGGL(prep_w, dim3(128), dim3(256), 0, stream, w, f, gw3);
  hipLaunchKernelGGL(conv_main, dim3(256), dim3(512), 0, stream, xb2, gw3, bias, out);
}